// Round 8
// baseline (331.213 us; speedup 1.0000x reference)
//
#include <hip/hip_runtime.h>
#include <math.h>

namespace {
constexpr int kB = 256;
constexpr int kN = 1024;
constexpr int kC = 512;
constexpr int kNP1 = kN + 1;
constexpr float kEPS = 1e-6f;
constexpr float kPOW = 0.9523809523809523f;    // ALPHA/(ALPHA+REG) = 1/1.05
constexpr float kSCALE = 28.8539008177792681f; // 20 * log2(e)

constexpr int kChunks = 64;       // blocks per batch
constexpr int kRowsPerBlk = 16;   // rows per block (4 per wave)

// ---- fast-path ws layout (bytes) ----
// vis8     : [0, 134,217,728)
// sim      : [+kB*kN*4)            (dustbin sim computed in terminal block)
// counters : [+kB*4)
constexpr size_t kVis8Bytes = (size_t)kB * kN * kC;
constexpr size_t kSimOffB = kVis8Bytes;
constexpr size_t kCntOffB = kSimOffB + (size_t)kB * kN * sizeof(float);
constexpr size_t kWsNeeded = kCntOffB + (size_t)kB * sizeof(unsigned);

// ---- fallback ws layout (floats) ----
constexpr size_t kFbSimOff = 0;
constexpr size_t kFbGammaOff = (size_t)kB * kNP1;
constexpr size_t kFbPartialOff = kFbGammaOff + (size_t)kB * kN;
constexpr int kNSplit = 4;
constexpr int kRowsPerSplit = kN / kNSplit;

typedef float f32x2 __attribute__((ext_vector_type(2)));
typedef float f32x4 __attribute__((ext_vector_type(4)));

// Agent-scope relaxed accesses: per-access coherence (sc-bits) past the
// non-coherent per-XCD L2s; NO cache-flush instructions are generated.
__device__ __forceinline__ void st_agent_u64(void* p, unsigned long long v) {
  __hip_atomic_store(reinterpret_cast<unsigned long long*>(p), v,
                     __ATOMIC_RELAXED, __HIP_MEMORY_SCOPE_AGENT);
}
__device__ __forceinline__ unsigned long long ld_agent_u64(const void* p) {
  return __hip_atomic_load(reinterpret_cast<const unsigned long long*>(p),
                           __ATOMIC_RELAXED, __HIP_MEMORY_SCOPE_AGENT);
}
__device__ __forceinline__ void st_agent_f32(float* p, float v) {
  __hip_atomic_store(p, v, __ATOMIC_RELAXED, __HIP_MEMORY_SCOPE_AGENT);
}
__device__ __forceinline__ float ld_agent_f32(const float* p) {
  return __hip_atomic_load(p, __ATOMIC_RELAXED, __HIP_MEMORY_SCOPE_AGENT);
}
}  // namespace

// ===========================================================================
// FUSED: 16384 blocks (64 per batch) x 256 threads (4 waves).
// Stage: 4 rows per wave (wave-per-row granularity): sims + fp8 copy, both
//   written with agent-scope stores. NT fp32 reads.
// Handshake: __syncthreads (drains vmcnt) -> relaxed atomicAdd; NO fences.
// Terminal (last block of batch): dustbin sim, Sinkhorn (4 n per thread),
//   einsum over vis8 via agent-scope loads, outputs.
// ===========================================================================
__global__ __launch_bounds__(256) void fused_uot2_kernel(
    const float* __restrict__ prompt,       // [B, C]
    const float* __restrict__ vis,          // [B, N, C]
    const float* __restrict__ dustbin,      // [C]
    float* __restrict__ sim,                // [B, N] (ws)
    unsigned char* __restrict__ vis8,       // [B, N, C] e4m3 (ws)
    unsigned* __restrict__ counters,        // [B] zeroed per launch (ws)
    float* __restrict__ p_obs,              // [B, C]
    float* __restrict__ mass_out) {         // [B]
  const int b = blockIdx.x >> 6;
  const int chunk = blockIdx.x & 63;
  const int t = threadIdx.x;
  const int w = t >> 6;        // wave 0..3
  const int lane = t & 63;
  const int coff = lane * 8;   // lane owns channels [coff, coff+8)

  __shared__ float gs[kN];            // gamma (terminal)
  __shared__ float red[4];
  __shared__ float pacc[4][64][8];    // 8 KB einsum partials
  __shared__ float simd_sh;           // dustbin sim
  __shared__ int is_last;

  // ---- prompt fragment + norm (once per wave) ----
  const float* prow = prompt + (size_t)b * kC;
  const f32x4 pa = *reinterpret_cast<const f32x4*>(prow + coff);
  const f32x4 pb = *reinterpret_cast<const f32x4*>(prow + coff + 4);
  float psq = pa.x * pa.x + pa.y * pa.y + pa.z * pa.z + pa.w * pa.w +
              pb.x * pb.x + pb.y * pb.y + pb.z * pb.z + pb.w * pb.w;
#pragma unroll
  for (int s = 1; s < 64; s <<= 1) psq += __shfl_xor(psq, s);
  const float pn = fmaxf(sqrtf(psq), 1e-12f);

  // ---- Stage: 4 rows per wave ----
  const int row0 = chunk * kRowsPerBlk + w * 4;
  const size_t base = ((size_t)b * kN + row0) * kC;
  const float* vptr = vis + base;
  unsigned char* v8ptr = vis8 + base;
  float* simw = sim + (size_t)b * kN + row0;

#pragma unroll
  for (int r = 0; r < 4; ++r) {
    const float* vrow = vptr + (size_t)r * kC;
    const f32x4 va = __builtin_nontemporal_load(
        reinterpret_cast<const f32x4*>(vrow + coff));
    const f32x4 vb = __builtin_nontemporal_load(
        reinterpret_cast<const f32x4*>(vrow + coff + 4));

    float dot = va.x * pa.x + va.y * pa.y + va.z * pa.z + va.w * pa.w +
                vb.x * pb.x + vb.y * pb.y + vb.z * pb.z + vb.w * pb.w;
    float vsq = va.x * va.x + va.y * va.y + va.z * va.z + va.w * va.w +
                vb.x * vb.x + vb.y * vb.y + vb.z * vb.z + vb.w * vb.w;

    int pk0 = __builtin_amdgcn_cvt_pk_fp8_f32(va.x, va.y, 0, false);
    pk0 = __builtin_amdgcn_cvt_pk_fp8_f32(va.z, va.w, pk0, true);
    int pk1 = __builtin_amdgcn_cvt_pk_fp8_f32(vb.x, vb.y, 0, false);
    pk1 = __builtin_amdgcn_cvt_pk_fp8_f32(vb.z, vb.w, pk1, true);
    const unsigned long long packed =
        ((unsigned long long)(unsigned)pk1 << 32) | (unsigned)pk0;
    st_agent_u64(v8ptr + (size_t)r * kC + coff, packed);

#pragma unroll
    for (int s = 1; s < 64; s <<= 1) {
      dot += __shfl_xor(dot, s);
      vsq += __shfl_xor(vsq, s);
    }
    if (lane == 0)
      st_agent_f32(simw + r, dot / (pn * fmaxf(sqrtf(vsq), 1e-12f)));
  }

  // ---- handshake: barrier drains vmcnt(0) per wave; then relaxed add ----
  __syncthreads();
  if (t == 0) {
    const unsigned old = atomicAdd(&counters[b], 1u);  // device-scope, relaxed
    is_last = (old == (unsigned)(kChunks - 1)) ? 1 : 0;
  }
  __syncthreads();
  if (!is_last) return;

  // ================= TERMINAL PHASE (one block per batch) =================

  // dustbin sim (wave 0; dustbin is tiny/cached)
  if (w == 0) {
    const f32x4 da = *reinterpret_cast<const f32x4*>(dustbin + coff);
    const f32x4 db = *reinterpret_cast<const f32x4*>(dustbin + coff + 4);
    float dot = da.x * pa.x + da.y * pa.y + da.z * pa.z + da.w * pa.w +
                db.x * pb.x + db.y * pb.y + db.z * pb.z + db.w * pb.w;
    float vsq = da.x * da.x + da.y * da.y + da.z * da.z + da.w * da.w +
                db.x * db.x + db.y * db.y + db.z * db.z + db.w * db.w;
#pragma unroll
    for (int s = 1; s < 64; s <<= 1) {
      dot += __shfl_xor(dot, s);
      vsq += __shfl_xor(vsq, s);
    }
    if (lane == 0) simd_sh = dot / (pn * fmaxf(sqrtf(vsq), 1e-12f));
  }

  // load my 4 sims -> K (agent-scope: bypass possibly-stale L1/L2)
  const float* simb = sim + (size_t)b * kN;
  float K[4], v[4];
#pragma unroll
  for (int j = 0; j < 4; ++j) {
    K[j] = exp2f((ld_agent_f32(simb + t + 256 * j) - 1.0f) * kSCALE);
    v[j] = 1.0f;
  }
  __syncthreads();  // publishes simd_sh
  const float Kd = (t == 0) ? exp2f((simd_sh - 1.0f) * kSCALE) : 0.0f;
  float vd = 1.0f, u = 1.0f;

#pragma unroll
  for (int it = 0; it < 3; ++it) {
    float partial = K[0] * v[0] + K[1] * v[1] + K[2] * v[2] + K[3] * v[3] +
                    Kd * vd;
#pragma unroll
    for (int s = 1; s < 64; s <<= 1) partial += __shfl_xor(partial, s);
    if (lane == 0) red[w] = partial;
    __syncthreads();
    const float Kv = red[0] + red[1] + red[2] + red[3];
    __syncthreads();
    u = exp2f(-kPOW * log2f(Kv + kEPS));
#pragma unroll
    for (int j = 0; j < 4; ++j)
      v[j] = exp2f(-kPOW * log2f(u * K[j] + kEPS));
    vd = exp2f(-kPOW * log2f(u * Kd + kEPS));
  }

  // gamma -> LDS; total_mass (n < N only; dustbin excluded by construction)
  float pm = 0.f;
#pragma unroll
  for (int j = 0; j < 4; ++j) {
    const float g = u * K[j] * v[j];
    gs[t + 256 * j] = g;
    pm += g;
  }
#pragma unroll
  for (int s = 1; s < 64; s <<= 1) pm += __shfl_xor(pm, s);
  if (lane == 0) red[w] = pm;
  __syncthreads();  // publishes gs + red
  if (t == 0) mass_out[b] = red[0] + red[1] + red[2] + red[3];

  // einsum: p_obs[c] = sum_n gs[n] * vis8[b,n,c]; wave w: n = w + 4k
  float acc[8] = {0.f, 0.f, 0.f, 0.f, 0.f, 0.f, 0.f, 0.f};
  const unsigned char* v8 = vis8 + (size_t)b * kN * kC + (size_t)coff;
#pragma unroll 16
  for (int k = 0; k < 256; ++k) {
    const int n = w + (k << 2);
    const float gn = gs[n];
    const unsigned long long d = ld_agent_u64(v8 + (size_t)n * kC);
    const unsigned wx = (unsigned)d;
    const unsigned wy = (unsigned)(d >> 32);
    const f32x2 f01 = __builtin_amdgcn_cvt_pk_f32_fp8(wx, false);
    const f32x2 f23 = __builtin_amdgcn_cvt_pk_f32_fp8(wx, true);
    const f32x2 f45 = __builtin_amdgcn_cvt_pk_f32_fp8(wy, false);
    const f32x2 f67 = __builtin_amdgcn_cvt_pk_f32_fp8(wy, true);
    acc[0] += gn * f01.x; acc[1] += gn * f01.y;
    acc[2] += gn * f23.x; acc[3] += gn * f23.y;
    acc[4] += gn * f45.x; acc[5] += gn * f45.y;
    acc[6] += gn * f67.x; acc[7] += gn * f67.y;
  }
#pragma unroll
  for (int j = 0; j < 8; ++j) pacc[w][lane][j] = acc[j];
  __syncthreads();
#pragma unroll
  for (int h = 0; h < 2; ++h) {
    const int c = t + 256 * h;
    float s = 0.f;
#pragma unroll
    for (int ww = 0; ww < 4; ++ww) s += pacc[ww][c >> 3][c & 7];
    p_obs[(size_t)b * kC + c] = s;
  }
}

// ===========================================================================
// FALLBACK (fp32 two-pass, round-1 proven; used only if ws too small)
// ===========================================================================
__global__ __launch_bounds__(256) void sim_kernel(
    const float* __restrict__ prompt, const float* __restrict__ vis,
    const float* __restrict__ dustbin, float* __restrict__ sim) {
  const int wid = threadIdx.x >> 6;
  const int lane = threadIdx.x & 63;
  const long long row = (long long)blockIdx.x * 4 + wid;
  if (row >= (long long)kB * kNP1) return;
  const int b = (int)(row / kNP1);
  const int n = (int)(row % kNP1);
  const float* vrow = (n < kN) ? (vis + ((size_t)b * kN + n) * kC) : dustbin;
  const float* prow = prompt + (size_t)b * kC;
  float dot = 0.f, vsq = 0.f, psq = 0.f;
#pragma unroll
  for (int h = 0; h < 2; ++h) {
    const int off = h * 256 + lane * 4;
    const float4 v4 = *reinterpret_cast<const float4*>(vrow + off);
    const float4 p4 = *reinterpret_cast<const float4*>(prow + off);
    dot += v4.x * p4.x + v4.y * p4.y + v4.z * p4.z + v4.w * p4.w;
    vsq += v4.x * v4.x + v4.y * v4.y + v4.z * v4.z + v4.w * v4.w;
    psq += p4.x * p4.x + p4.y * p4.y + p4.z * p4.z + p4.w * p4.w;
  }
#pragma unroll
  for (int s = 1; s < 64; s <<= 1) {
    dot += __shfl_xor(dot, s);
    vsq += __shfl_xor(vsq, s);
    psq += __shfl_xor(psq, s);
  }
  if (lane == 0) {
    const float pn = fmaxf(sqrtf(psq), 1e-12f);
    const float vn = fmaxf(sqrtf(vsq), 1e-12f);
    sim[row] = dot / (pn * vn);
  }
}

__global__ __launch_bounds__(1024) void sinkhorn_kernel(
    const float* __restrict__ sim, float* __restrict__ gamma,
    float* __restrict__ mass_out) {
  const int b = blockIdx.x;
  const int t = threadIdx.x;
  __shared__ float red[16];
  const float* simb = sim + (size_t)b * kNP1;
  const float K0 = exp2f((simb[t] - 1.0f) * kSCALE);
  const float K1 = (t == 0) ? exp2f((simb[kN] - 1.0f) * kSCALE) : 0.0f;
  float v0 = 1.0f, v1 = 1.0f, u = 1.0f;
  for (int it = 0; it < 3; ++it) {
    float partial = K0 * v0 + K1 * v1;
#pragma unroll
    for (int s = 1; s < 64; s <<= 1) partial += __shfl_xor(partial, s);
    if ((t & 63) == 0) red[t >> 6] = partial;
    __syncthreads();
    float Kv = 0.f;
#pragma unroll
    for (int w = 0; w < 16; ++w) Kv += red[w];
    __syncthreads();
    u = exp2f(-kPOW * log2f(Kv + kEPS));
    v0 = exp2f(-kPOW * log2f(u * K0 + kEPS));
    v1 = exp2f(-kPOW * log2f(u * K1 + kEPS));
  }
  const float g0 = u * K0 * v0;
  gamma[(size_t)b * kN + t] = g0;
  float partial = g0;
#pragma unroll
  for (int s = 1; s < 64; s <<= 1) partial += __shfl_xor(partial, s);
  if ((t & 63) == 0) red[t >> 6] = partial;
  __syncthreads();
  if (t == 0) {
    float m = 0.f;
#pragma unroll
    for (int w = 0; w < 16; ++w) m += red[w];
    mass_out[b] = m;
  }
}

__global__ __launch_bounds__(512) void pobs_kernel(
    const float* __restrict__ vis, const float* __restrict__ gamma,
    float* __restrict__ partial) {
  const int b = blockIdx.x / kNSplit;
  const int s = blockIdx.x % kNSplit;
  const int c = threadIdx.x;
  __shared__ float gsm[kRowsPerSplit];
  const float* g = gamma + (size_t)b * kN + (size_t)s * kRowsPerSplit;
  for (int i = threadIdx.x; i < kRowsPerSplit; i += 512) gsm[i] = g[i];
  __syncthreads();
  const float* vbase = vis + ((size_t)b * kN + (size_t)s * kRowsPerSplit) * kC;
  float acc = 0.f;
#pragma unroll 8
  for (int n = 0; n < kRowsPerSplit; ++n)
    acc += gsm[n] * vbase[(size_t)n * kC + c];
  partial[(size_t)blockIdx.x * kC + c] = acc;
}

__global__ __launch_bounds__(256) void reduce_kernel(
    const float* __restrict__ partial, float* __restrict__ p_obs) {
  const int i = blockIdx.x * 256 + threadIdx.x;
  if (i >= kB * kC) return;
  const int b = i / kC;
  const int c = i % kC;
  float s = 0.f;
#pragma unroll
  for (int k = 0; k < kNSplit; ++k)
    s += partial[((size_t)(b * kNSplit + k)) * kC + c];
  p_obs[i] = s;
}

// ===========================================================================

extern "C" void kernel_launch(void* const* d_in, const int* in_sizes, int n_in,
                              void* d_out, int out_size, void* d_ws,
                              size_t ws_size, hipStream_t stream) {
  const float* prompt = (const float*)d_in[0];
  const float* vis = (const float*)d_in[1];
  const float* dustbin = (const float*)d_in[2];
  float* out = (float*)d_out;  // p_obs [B*C] then total_mass [B]

  if (ws_size >= kWsNeeded) {
    unsigned char* ws8 = (unsigned char*)d_ws;
    unsigned char* vis8 = ws8;
    float* sim = (float*)(ws8 + kSimOffB);
    unsigned* counters = (unsigned*)(ws8 + kCntOffB);
    hipMemsetAsync(counters, 0, kB * sizeof(unsigned), stream);
    fused_uot2_kernel<<<kB * kChunks, 256, 0, stream>>>(
        prompt, vis, dustbin, sim, vis8, counters, out,
        out + (size_t)kB * kC);
  } else {
    float* ws = (float*)d_ws;
    float* sim = ws + kFbSimOff;
    float* gamma = ws + kFbGammaOff;
    float* partial = ws + kFbPartialOff;
    const long long rows = (long long)kB * kNP1;
    sim_kernel<<<(int)((rows + 3) / 4), 256, 0, stream>>>(prompt, vis,
                                                          dustbin, sim);
    sinkhorn_kernel<<<kB, 1024, 0, stream>>>(sim, gamma, out + (size_t)kB * kC);
    pobs_kernel<<<kB * kNSplit, 512, 0, stream>>>(vis, gamma, partial);
    reduce_kernel<<<(kB * kC + 255) / 256, 256, 0, stream>>>(partial, out);
  }
}

// Round 9
// 149.994 us; speedup vs baseline: 2.2082x; 2.2082x over previous
//
#include <hip/hip_runtime.h>
#include <math.h>

namespace {
constexpr int kB = 256;
constexpr int kN = 1024;
constexpr int kC = 512;
constexpr int kNP1 = kN + 1;  // 1025 (visual rows + dustbin)
constexpr float kEPS = 1e-6f;
constexpr float kPOW = 0.9523809523809523f;  // ALPHA/(ALPHA+REG) = 1/1.05
constexpr float kLOG2E = 1.44269504088896341f;

// ---- fast-path ws layout (bytes) ----
constexpr size_t kVis8Bytes = (size_t)kB * kN * kC;  // 134,217,728
constexpr size_t kSimOffB = kVis8Bytes;
constexpr size_t kWsNeeded = kVis8Bytes + (size_t)kB * kNP1 * sizeof(float);

// ---- fallback ws layout (floats) ----
constexpr size_t kFbSimOff = 0;
constexpr size_t kFbGammaOff = (size_t)kB * kNP1;
constexpr size_t kFbPartialOff = kFbGammaOff + (size_t)kB * kN;
constexpr int kNSplit = 4;
constexpr int kRowsPerSplit = kN / kNSplit;  // 256

typedef float f32x2 __attribute__((ext_vector_type(2)));
typedef float f32x4 __attribute__((ext_vector_type(4)));
}  // namespace

// ===========================================================================
// FAST PATH (round-2 structure; ONLY change: K1 = 2 rows per wave, loads for
// both rows issued up-front to double memory-level parallelism; the six
// shuffle-reduce chains (dot/vsq/psq x 2 rows) interleave).
// ===========================================================================

// K1: sim[b,n] for all 1025*256 rows; also write e4m3 copy of vis (n < N).
// One wave per TWO consecutive rows; lane owns channels [lane*8, lane*8+8).
// Total rows = 262400 = 8 * 32800 exactly.
__global__ __launch_bounds__(256) void sim_fp8_kernel(
    const float* __restrict__ prompt,       // [B, C]
    const float* __restrict__ vis,          // [B, N, C]
    const float* __restrict__ dustbin,      // [C]
    float* __restrict__ sim,                // [B, NP1]
    unsigned char* __restrict__ vis8) {     // [B, N, C] e4m3
  const int wid = threadIdx.x >> 6;
  const int lane = threadIdx.x & 63;
  const int off = lane * 8;

  const long long row0 = (long long)blockIdx.x * 8 + wid * 2;
  const long long row1 = row0 + 1;
  const int b0 = (int)(row0 / kNP1), n0 = (int)(row0 % kNP1);
  const int b1 = (int)(row1 / kNP1), n1 = (int)(row1 % kNP1);

  const float* vrow0 = (n0 < kN) ? (vis + ((size_t)b0 * kN + n0) * kC) : dustbin;
  const float* vrow1 = (n1 < kN) ? (vis + ((size_t)b1 * kN + n1) * kC) : dustbin;

  // ---- issue all global loads up front (2 rows x 32B + 2 prompt x 32B) ----
  f32x4 va0, vb0, va1, vb1;
  if (n0 < kN) {
    va0 = __builtin_nontemporal_load(reinterpret_cast<const f32x4*>(vrow0 + off));
    vb0 = __builtin_nontemporal_load(reinterpret_cast<const f32x4*>(vrow0 + off + 4));
  } else {
    va0 = *reinterpret_cast<const f32x4*>(vrow0 + off);
    vb0 = *reinterpret_cast<const f32x4*>(vrow0 + off + 4);
  }
  if (n1 < kN) {
    va1 = __builtin_nontemporal_load(reinterpret_cast<const f32x4*>(vrow1 + off));
    vb1 = __builtin_nontemporal_load(reinterpret_cast<const f32x4*>(vrow1 + off + 4));
  } else {
    va1 = *reinterpret_cast<const f32x4*>(vrow1 + off);
    vb1 = *reinterpret_cast<const f32x4*>(vrow1 + off + 4);
  }
  const float* prow0 = prompt + (size_t)b0 * kC;
  const float* prow1 = prompt + (size_t)b1 * kC;
  const f32x4 pa0 = *reinterpret_cast<const f32x4*>(prow0 + off);
  const f32x4 pb0 = *reinterpret_cast<const f32x4*>(prow0 + off + 4);
  const f32x4 pa1 = *reinterpret_cast<const f32x4*>(prow1 + off);
  const f32x4 pb1 = *reinterpret_cast<const f32x4*>(prow1 + off + 4);

  // ---- per-row partials ----
  float dot0 = va0.x * pa0.x + va0.y * pa0.y + va0.z * pa0.z + va0.w * pa0.w +
               vb0.x * pb0.x + vb0.y * pb0.y + vb0.z * pb0.z + vb0.w * pb0.w;
  float vsq0 = va0.x * va0.x + va0.y * va0.y + va0.z * va0.z + va0.w * va0.w +
               vb0.x * vb0.x + vb0.y * vb0.y + vb0.z * vb0.z + vb0.w * vb0.w;
  float psq0 = pa0.x * pa0.x + pa0.y * pa0.y + pa0.z * pa0.z + pa0.w * pa0.w +
               pb0.x * pb0.x + pb0.y * pb0.y + pb0.z * pb0.z + pb0.w * pb0.w;
  float dot1 = va1.x * pa1.x + va1.y * pa1.y + va1.z * pa1.z + va1.w * pa1.w +
               vb1.x * pb1.x + vb1.y * pb1.y + vb1.z * pb1.z + vb1.w * pb1.w;
  float vsq1 = va1.x * va1.x + va1.y * va1.y + va1.z * va1.z + va1.w * va1.w +
               vb1.x * vb1.x + vb1.y * vb1.y + vb1.z * vb1.z + vb1.w * vb1.w;
  float psq1 = pa1.x * pa1.x + pa1.y * pa1.y + pa1.z * pa1.z + pa1.w * pa1.w +
               pb1.x * pb1.x + pb1.y * pb1.y + pb1.z * pb1.z + pb1.w * pb1.w;

  // ---- e4m3 copies (real visual rows only), stores issued before reduce ----
  if (n0 < kN) {
    int pk0 = __builtin_amdgcn_cvt_pk_fp8_f32(va0.x, va0.y, 0, false);
    pk0 = __builtin_amdgcn_cvt_pk_fp8_f32(va0.z, va0.w, pk0, true);
    int pk1 = __builtin_amdgcn_cvt_pk_fp8_f32(vb0.x, vb0.y, 0, false);
    pk1 = __builtin_amdgcn_cvt_pk_fp8_f32(vb0.z, vb0.w, pk1, true);
    uint2 w;
    w.x = (unsigned)pk0;
    w.y = (unsigned)pk1;
    *reinterpret_cast<uint2*>(vis8 + ((size_t)b0 * kN + n0) * kC + off) = w;
  }
  if (n1 < kN) {
    int pk0 = __builtin_amdgcn_cvt_pk_fp8_f32(va1.x, va1.y, 0, false);
    pk0 = __builtin_amdgcn_cvt_pk_fp8_f32(va1.z, va1.w, pk0, true);
    int pk1 = __builtin_amdgcn_cvt_pk_fp8_f32(vb1.x, vb1.y, 0, false);
    pk1 = __builtin_amdgcn_cvt_pk_fp8_f32(vb1.z, vb1.w, pk1, true);
    uint2 w;
    w.x = (unsigned)pk0;
    w.y = (unsigned)pk1;
    *reinterpret_cast<uint2*>(vis8 + ((size_t)b1 * kN + n1) * kC + off) = w;
  }

  // ---- six interleaved shuffle-reduce chains ----
#pragma unroll
  for (int s = 1; s < 64; s <<= 1) {
    dot0 += __shfl_xor(dot0, s);
    vsq0 += __shfl_xor(vsq0, s);
    psq0 += __shfl_xor(psq0, s);
    dot1 += __shfl_xor(dot1, s);
    vsq1 += __shfl_xor(vsq1, s);
    psq1 += __shfl_xor(psq1, s);
  }
  if (lane == 0) {
    sim[row0] = dot0 / (fmaxf(sqrtf(psq0), 1e-12f) * fmaxf(sqrtf(vsq0), 1e-12f));
    sim[row1] = dot1 / (fmaxf(sqrtf(psq1), 1e-12f) * fmaxf(sqrtf(vsq1), 1e-12f));
  }
}

// K2: per-batch Sinkhorn + einsum + both outputs, one 1024-thread block per b.
// (round-2 verbatim)
__global__ __launch_bounds__(1024) void sinkhorn_pobs_kernel(
    const float* __restrict__ sim,          // [B, NP1]
    const unsigned char* __restrict__ vis8, // [B, N, C] e4m3
    float* __restrict__ p_obs,              // [B, C]
    float* __restrict__ mass_out) {         // [B]
  const int b = blockIdx.x;
  const int t = threadIdx.x;
  __shared__ float red[16];
  __shared__ float gs[kN];
  __shared__ float lds[16][64][8];  // 32 KB

  const float* simb = sim + (size_t)b * kNP1;
  const float K0 = exp2f((simb[t] - 1.0f) * (20.0f * kLOG2E));
  const float Kd = (t == 0) ? exp2f((simb[kN] - 1.0f) * (20.0f * kLOG2E)) : 0.0f;
  float v0 = 1.0f, vd = 1.0f, u = 1.0f;

#pragma unroll
  for (int it = 0; it < 3; ++it) {
    float partial = K0 * v0 + Kd * vd;
#pragma unroll
    for (int s = 1; s < 64; s <<= 1) partial += __shfl_xor(partial, s);
    if ((t & 63) == 0) red[t >> 6] = partial;
    __syncthreads();
    float Kv = 0.f;
#pragma unroll
    for (int w = 0; w < 16; ++w) Kv += red[w];
    __syncthreads();
    u = exp2f(-kPOW * log2f(Kv + kEPS));
    v0 = exp2f(-kPOW * log2f(u * K0 + kEPS));
    vd = exp2f(-kPOW * log2f(u * Kd + kEPS));
  }

  const float g = u * K0 * v0;  // gamma for n = t (< N always)
  gs[t] = g;

  float pm = g;
#pragma unroll
  for (int s = 1; s < 64; s <<= 1) pm += __shfl_xor(pm, s);
  if ((t & 63) == 0) red[t >> 6] = pm;
  __syncthreads();
  if (t == 0) {
    float m = 0.f;
#pragma unroll
    for (int w = 0; w < 16; ++w) m += red[w];
    mass_out[b] = m;
  }

  // einsum: p_obs[c] = sum_n gs[n] * vis8[b,n,c]
  const int sub = t >> 6;
  const int cq = t & 63;
  float acc[8] = {0.f, 0.f, 0.f, 0.f, 0.f, 0.f, 0.f, 0.f};
  const unsigned char* vbase = vis8 + (size_t)b * kN * kC + (size_t)cq * 8;
#pragma unroll 4
  for (int k = 0; k < 64; ++k) {
    const int n = sub + (k << 4);
    const float gn = gs[n];
    const uint2 w = *reinterpret_cast<const uint2*>(vbase + (size_t)n * kC);
    const f32x2 f01 = __builtin_amdgcn_cvt_pk_f32_fp8(w.x, false);
    const f32x2 f23 = __builtin_amdgcn_cvt_pk_f32_fp8(w.x, true);
    const f32x2 f45 = __builtin_amdgcn_cvt_pk_f32_fp8(w.y, false);
    const f32x2 f67 = __builtin_amdgcn_cvt_pk_f32_fp8(w.y, true);
    acc[0] += gn * f01.x; acc[1] += gn * f01.y;
    acc[2] += gn * f23.x; acc[3] += gn * f23.y;
    acc[4] += gn * f45.x; acc[5] += gn * f45.y;
    acc[6] += gn * f67.x; acc[7] += gn * f67.y;
  }
#pragma unroll
  for (int j = 0; j < 8; ++j) lds[sub][cq][j] = acc[j];
  __syncthreads();
  if (t < 512) {
    float s = 0.f;
#pragma unroll
    for (int ss = 0; ss < 16; ++ss) s += lds[ss][t >> 3][t & 7];
    p_obs[(size_t)b * kC + t] = s;
  }
}

// ===========================================================================
// FALLBACK PATH (round-1 fp32 two-pass; used only if ws too small)
// ===========================================================================

__global__ __launch_bounds__(256) void sim_kernel(
    const float* __restrict__ prompt, const float* __restrict__ vis,
    const float* __restrict__ dustbin, float* __restrict__ sim) {
  const int wid = threadIdx.x >> 6;
  const int lane = threadIdx.x & 63;
  const long long row = (long long)blockIdx.x * 4 + wid;
  if (row >= (long long)kB * kNP1) return;
  const int b = (int)(row / kNP1);
  const int n = (int)(row % kNP1);
  const float* vrow = (n < kN) ? (vis + ((size_t)b * kN + n) * kC) : dustbin;
  const float* prow = prompt + (size_t)b * kC;
  float dot = 0.f, vsq = 0.f, psq = 0.f;
#pragma unroll
  for (int h = 0; h < 2; ++h) {
    const int off = h * 256 + lane * 4;
    const float4 v4 = *reinterpret_cast<const float4*>(vrow + off);
    const float4 p4 = *reinterpret_cast<const float4*>(prow + off);
    dot += v4.x * p4.x + v4.y * p4.y + v4.z * p4.z + v4.w * p4.w;
    vsq += v4.x * v4.x + v4.y * v4.y + v4.z * v4.z + v4.w * v4.w;
    psq += p4.x * p4.x + p4.y * p4.y + p4.z * p4.z + p4.w * p4.w;
  }
#pragma unroll
  for (int s = 1; s < 64; s <<= 1) {
    dot += __shfl_xor(dot, s);
    vsq += __shfl_xor(vsq, s);
    psq += __shfl_xor(psq, s);
  }
  if (lane == 0) {
    const float pn = fmaxf(sqrtf(psq), 1e-12f);
    const float vn = fmaxf(sqrtf(vsq), 1e-12f);
    sim[row] = dot / (pn * vn);
  }
}

__global__ __launch_bounds__(1024) void sinkhorn_kernel(
    const float* __restrict__ sim, float* __restrict__ gamma,
    float* __restrict__ mass_out) {
  const int b = blockIdx.x;
  const int t = threadIdx.x;
  __shared__ float red[16];
  const float* simb = sim + (size_t)b * kNP1;
  const float K0 = exp2f((simb[t] - 1.0f) * (20.0f * kLOG2E));
  const float K1 = (t == 0) ? exp2f((simb[kN] - 1.0f) * (20.0f * kLOG2E)) : 0.0f;
  float v0 = 1.0f, v1 = 1.0f, u = 1.0f;
  for (int it = 0; it < 3; ++it) {
    float partial = K0 * v0 + K1 * v1;
#pragma unroll
    for (int s = 1; s < 64; s <<= 1) partial += __shfl_xor(partial, s);
    if ((t & 63) == 0) red[t >> 6] = partial;
    __syncthreads();
    float Kv = 0.f;
#pragma unroll
    for (int w = 0; w < 16; ++w) Kv += red[w];
    __syncthreads();
    u = exp2f(-kPOW * log2f(Kv + kEPS));
    v0 = exp2f(-kPOW * log2f(u * K0 + kEPS));
    v1 = exp2f(-kPOW * log2f(u * K1 + kEPS));
  }
  const float g0 = u * K0 * v0;
  gamma[(size_t)b * kN + t] = g0;
  float partial = g0;
#pragma unroll
  for (int s = 1; s < 64; s <<= 1) partial += __shfl_xor(partial, s);
  if ((t & 63) == 0) red[t >> 6] = partial;
  __syncthreads();
  if (t == 0) {
    float m = 0.f;
#pragma unroll
    for (int w = 0; w < 16; ++w) m += red[w];
    mass_out[b] = m;
  }
}

__global__ __launch_bounds__(512) void pobs_kernel(
    const float* __restrict__ vis, const float* __restrict__ gamma,
    float* __restrict__ partial) {
  const int b = blockIdx.x / kNSplit;
  const int s = blockIdx.x % kNSplit;
  const int c = threadIdx.x;
  __shared__ float gsm[kRowsPerSplit];
  const float* g = gamma + (size_t)b * kN + (size_t)s * kRowsPerSplit;
  for (int i = threadIdx.x; i < kRowsPerSplit; i += 512) gsm[i] = g[i];
  __syncthreads();
  const float* vbase = vis + ((size_t)b * kN + (size_t)s * kRowsPerSplit) * kC;
  float acc = 0.f;
#pragma unroll 8
  for (int n = 0; n < kRowsPerSplit; ++n)
    acc += gsm[n] * vbase[(size_t)n * kC + c];
  partial[(size_t)blockIdx.x * kC + c] = acc;
}

__global__ __launch_bounds__(256) void reduce_kernel(
    const float* __restrict__ partial, float* __restrict__ p_obs) {
  const int i = blockIdx.x * 256 + threadIdx.x;
  if (i >= kB * kC) return;
  const int b = i / kC;
  const int c = i % kC;
  float s = 0.f;
#pragma unroll
  for (int k = 0; k < kNSplit; ++k)
    s += partial[((size_t)(b * kNSplit + k)) * kC + c];
  p_obs[i] = s;
}

// ===========================================================================

extern "C" void kernel_launch(void* const* d_in, const int* in_sizes, int n_in,
                              void* d_out, int out_size, void* d_ws,
                              size_t ws_size, hipStream_t stream) {
  const float* prompt = (const float*)d_in[0];
  const float* vis = (const float*)d_in[1];
  const float* dustbin = (const float*)d_in[2];
  float* out = (float*)d_out;  // p_obs [B*C] then total_mass [B]

  if (ws_size >= kWsNeeded) {
    unsigned char* vis8 = (unsigned char*)d_ws;
    float* sim = (float*)((unsigned char*)d_ws + kSimOffB);
    const long long rows = (long long)kB * kNP1;  // 262400 = 8 * 32800
    sim_fp8_kernel<<<(int)(rows / 8), 256, 0, stream>>>(
        prompt, vis, dustbin, sim, vis8);
    sinkhorn_pobs_kernel<<<kB, 1024, 0, stream>>>(
        sim, vis8, out, out + (size_t)kB * kC);
  } else {
    float* ws = (float*)d_ws;
    float* sim = ws + kFbSimOff;
    float* gamma = ws + kFbGammaOff;
    float* partial = ws + kFbPartialOff;
    const long long rows = (long long)kB * kNP1;
    sim_kernel<<<(int)((rows + 3) / 4), 256, 0, stream>>>(prompt, vis,
                                                          dustbin, sim);
    sinkhorn_kernel<<<kB, 1024, 0, stream>>>(sim, gamma, out + (size_t)kB * kC);
    pobs_kernel<<<kB * kNSplit, 512, 0, stream>>>(vis, gamma, partial);
    reduce_kernel<<<(kB * kC + 255) / 256, 256, 0, stream>>>(partial, out);
  }
}

// Round 10
// 110.895 us; speedup vs baseline: 2.9867x; 1.3526x over previous
//
#include <hip/hip_runtime.h>
#include <math.h>

namespace {
constexpr int kB = 256;
constexpr int kN = 1024;
constexpr int kC = 512;
constexpr int kNP1 = kN + 1;  // 1025 (visual rows + dustbin)
constexpr float kEPS = 1e-6f;
constexpr float kPOW = 0.9523809523809523f;    // ALPHA/(ALPHA+REG) = 1/1.05
constexpr float kSCALE = 28.8539008177792681f; // 20 * log2(e)

// series constants: gamma = u*K*(u*K+eps)^-POW, K = 2^-30 * Ks
//   p_obs = u*2^-30*eps^-POW * [M1 - POW*z*M2 + c2*z^2*M3 - c3*z^3*M4],
//   z = u * 2^-30/eps,  M_j = sum_n Ks_n^j * vis_nc
constexpr float kBaseC = 4.823755e-4f;   // 2^-30 * eps^-POW
constexpr float kZC = 9.3132257e-4f;     // 2^-30 / eps
constexpr float kC2 = 0.92970522f;       // POW(POW+1)/2
constexpr float kC3 = 0.91494840f;       // POW(POW+1)(POW+2)/6

// ---- fast-path ws layout (bytes) ----
// sim      : [0, kB*kNP1*4)                    1,049,600 B
// partials : [+1024 blocks * 4 moments * 512c * 4B)  8,388,608 B
constexpr size_t kSimBytes = (size_t)kB * kNP1 * sizeof(float);
constexpr size_t kPartOffB = kSimBytes;
constexpr size_t kWsNeeded = kSimBytes + (size_t)kB * 4 * 4 * kC * sizeof(float);

// ---- fallback ws layout (floats) ----
constexpr size_t kFbSimOff = 0;
constexpr size_t kFbGammaOff = (size_t)kB * kNP1;
constexpr size_t kFbPartialOff = kFbGammaOff + (size_t)kB * kN;
constexpr int kNSplit = 4;
constexpr int kRowsPerSplit = kN / kNSplit;  // 256

typedef float f32x4 __attribute__((ext_vector_type(4)));
}  // namespace

// ===========================================================================
// K1: sims + 4 K-weighted moment partials, single pass over vis.
// 1024 blocks (4 per batch) x 256 threads (4 waves); wave owns 64 rows;
// lane owns channels [lane*8, lane*8+8). Moments accumulate in registers.
// ===========================================================================
__global__ __launch_bounds__(256) void sim_moment_kernel(
    const float* __restrict__ prompt,    // [B, C]
    const float* __restrict__ vis,       // [B, N, C]
    const float* __restrict__ dustbin,   // [C]
    float* __restrict__ sim,             // [B, NP1] (ws)
    float* __restrict__ partials) {      // [1024][4][512] (ws)
  const int w = threadIdx.x >> 6;        // wave 0..3
  const int lane = threadIdx.x & 63;
  const int b = blockIdx.x >> 2;
  const int chunk = blockIdx.x & 3;
  const int coff = lane * 8;

  __shared__ float lds[4][4][kC];  // 32 KB [wave][moment][channel]

  // prompt fragment + norm (once per wave)
  const float* prow = prompt + (size_t)b * kC;
  const f32x4 pa = *reinterpret_cast<const f32x4*>(prow + coff);
  const f32x4 pb = *reinterpret_cast<const f32x4*>(prow + coff + 4);
  float psq = pa.x * pa.x + pa.y * pa.y + pa.z * pa.z + pa.w * pa.w +
              pb.x * pb.x + pb.y * pb.y + pb.z * pb.z + pb.w * pb.w;
#pragma unroll
  for (int s = 1; s < 64; s <<= 1) psq += __shfl_xor(psq, s);
  const float pn = fmaxf(sqrtf(psq), 1e-12f);

  const int n0 = chunk * 256 + w * 64;   // first row of this wave
  const float* vbase = vis + ((size_t)b * kN + n0) * kC;
  float* simw = sim + (size_t)b * kNP1 + n0;

  float m1[8] = {0, 0, 0, 0, 0, 0, 0, 0};
  float m2[8] = {0, 0, 0, 0, 0, 0, 0, 0};
  float m3[8] = {0, 0, 0, 0, 0, 0, 0, 0};
  float m4[8] = {0, 0, 0, 0, 0, 0, 0, 0};

#pragma unroll 2
  for (int r = 0; r < 64; ++r) {
    const float* vrow = vbase + (size_t)r * kC;
    const f32x4 va = __builtin_nontemporal_load(
        reinterpret_cast<const f32x4*>(vrow + coff));
    const f32x4 vb = __builtin_nontemporal_load(
        reinterpret_cast<const f32x4*>(vrow + coff + 4));

    float dot = va.x * pa.x + va.y * pa.y + va.z * pa.z + va.w * pa.w +
                vb.x * pb.x + vb.y * pb.y + vb.z * pb.z + vb.w * pb.w;
    float vsq = va.x * va.x + va.y * va.y + va.z * va.z + va.w * va.w +
                vb.x * vb.x + vb.y * vb.y + vb.z * vb.z + vb.w * vb.w;
#pragma unroll
    for (int s = 1; s < 64; s <<= 1) {
      dot += __shfl_xor(dot, s);
      vsq += __shfl_xor(vsq, s);
    }
    const float sm = dot / (pn * fmaxf(sqrtf(vsq), 1e-12f));
    if (lane == 0) simw[r] = sm;

    // Ks = 2^30 * K = exp2(SCALE*(sim-1) + 30); range ~[0.03, 150]
    const float Ks = exp2f(kSCALE * (sm - 1.0f) + 30.0f);
    const float Ks2 = Ks * Ks;
    const float Ks3 = Ks2 * Ks;
    const float Ks4 = Ks2 * Ks2;
    m1[0] += Ks * va.x; m1[1] += Ks * va.y; m1[2] += Ks * va.z; m1[3] += Ks * va.w;
    m1[4] += Ks * vb.x; m1[5] += Ks * vb.y; m1[6] += Ks * vb.z; m1[7] += Ks * vb.w;
    m2[0] += Ks2 * va.x; m2[1] += Ks2 * va.y; m2[2] += Ks2 * va.z; m2[3] += Ks2 * va.w;
    m2[4] += Ks2 * vb.x; m2[5] += Ks2 * vb.y; m2[6] += Ks2 * vb.z; m2[7] += Ks2 * vb.w;
    m3[0] += Ks3 * va.x; m3[1] += Ks3 * va.y; m3[2] += Ks3 * va.z; m3[3] += Ks3 * va.w;
    m3[4] += Ks3 * vb.x; m3[5] += Ks3 * vb.y; m3[6] += Ks3 * vb.z; m3[7] += Ks3 * vb.w;
    m4[0] += Ks4 * va.x; m4[1] += Ks4 * va.y; m4[2] += Ks4 * va.z; m4[3] += Ks4 * va.w;
    m4[4] += Ks4 * vb.x; m4[5] += Ks4 * vb.y; m4[6] += Ks4 * vb.z; m4[7] += Ks4 * vb.w;
  }

  // dustbin sim (one wave per batch; excluded from moments/outputs)
  if (chunk == 3 && w == 3) {
    const f32x4 da = *reinterpret_cast<const f32x4*>(dustbin + coff);
    const f32x4 db = *reinterpret_cast<const f32x4*>(dustbin + coff + 4);
    float dot = da.x * pa.x + da.y * pa.y + da.z * pa.z + da.w * pa.w +
                db.x * pb.x + db.y * pb.y + db.z * pb.z + db.w * pb.w;
    float vsq = da.x * da.x + da.y * da.y + da.z * da.z + da.w * da.w +
                db.x * db.x + db.y * db.y + db.z * db.z + db.w * db.w;
#pragma unroll
    for (int s = 1; s < 64; s <<= 1) {
      dot += __shfl_xor(dot, s);
      vsq += __shfl_xor(vsq, s);
    }
    if (lane == 0)
      sim[(size_t)b * kNP1 + kN] = dot / (pn * fmaxf(sqrtf(vsq), 1e-12f));
  }

  // block-level moment reduce via LDS
#pragma unroll
  for (int j = 0; j < 8; ++j) {
    lds[w][0][coff + j] = m1[j];
    lds[w][1][coff + j] = m2[j];
    lds[w][2][coff + j] = m3[j];
    lds[w][3][coff + j] = m4[j];
  }
  __syncthreads();
#pragma unroll
  for (int h = 0; h < 2; ++h) {
    const int c = (int)threadIdx.x + h * 256;
#pragma unroll
    for (int m = 0; m < 4; ++m) {
      const float s =
          lds[0][m][c] + lds[1][m][c] + lds[2][m][c] + lds[3][m][c];
      partials[((size_t)blockIdx.x * 4 + m) * kC + c] = s;
    }
  }
}

// ===========================================================================
// K2': exact Sinkhorn from sims (unchanged math) -> u; exact total_mass;
// p_obs from the 4-moment series. One 1024-thread block per batch.
// ===========================================================================
__global__ __launch_bounds__(1024) void sinkhorn_combine_kernel(
    const float* __restrict__ sim,        // [B, NP1]
    const float* __restrict__ partials,   // [1024][4][512]
    float* __restrict__ p_obs,            // [B, C]
    float* __restrict__ mass_out) {       // [B]
  const int b = blockIdx.x;
  const int t = threadIdx.x;
  __shared__ float red[16];

  const float* simb = sim + (size_t)b * kNP1;
  const float K0 = exp2f((simb[t] - 1.0f) * kSCALE);
  const float Kd = (t == 0) ? exp2f((simb[kN] - 1.0f) * kSCALE) : 0.0f;
  float v0 = 1.0f, vd = 1.0f, u = 1.0f;

#pragma unroll
  for (int it = 0; it < 3; ++it) {
    float partial = K0 * v0 + Kd * vd;
#pragma unroll
    for (int s = 1; s < 64; s <<= 1) partial += __shfl_xor(partial, s);
    if ((t & 63) == 0) red[t >> 6] = partial;
    __syncthreads();
    float Kv = 0.f;
#pragma unroll
    for (int w = 0; w < 16; ++w) Kv += red[w];
    __syncthreads();
    u = exp2f(-kPOW * log2f(Kv + kEPS));
    v0 = exp2f(-kPOW * log2f(u * K0 + kEPS));
    vd = exp2f(-kPOW * log2f(u * Kd + kEPS));
  }

  // exact gamma for n = t (< N always) -> total_mass
  const float g = u * K0 * v0;
  float pm = g;
#pragma unroll
  for (int s = 1; s < 64; s <<= 1) pm += __shfl_xor(pm, s);
  if ((t & 63) == 0) red[t >> 6] = pm;
  __syncthreads();
  if (t == 0) {
    float m = 0.f;
#pragma unroll
    for (int w = 0; w < 16; ++w) m += red[w];
    mass_out[b] = m;
  }

  // p_obs via moment series
  if (t < kC) {
    float M1 = 0.f, M2 = 0.f, M3 = 0.f, M4 = 0.f;
#pragma unroll
    for (int k = 0; k < 4; ++k) {
      const size_t blk = (size_t)(b * 4 + k);
      M1 += partials[(blk * 4 + 0) * kC + t];
      M2 += partials[(blk * 4 + 1) * kC + t];
      M3 += partials[(blk * 4 + 2) * kC + t];
      M4 += partials[(blk * 4 + 3) * kC + t];
    }
    const float z = u * kZC;
    const float base = u * kBaseC;
    const float p =
        base * (M1 + z * (-kPOW * M2 + z * (kC2 * M3 - z * (kC3 * M4))));
    p_obs[(size_t)b * kC + t] = p;
  }
}

// ===========================================================================
// FALLBACK (fp32 two-pass, round-1 proven; used only if ws too small)
// ===========================================================================
__global__ __launch_bounds__(256) void sim_kernel(
    const float* __restrict__ prompt, const float* __restrict__ vis,
    const float* __restrict__ dustbin, float* __restrict__ sim) {
  const int wid = threadIdx.x >> 6;
  const int lane = threadIdx.x & 63;
  const long long row = (long long)blockIdx.x * 4 + wid;
  if (row >= (long long)kB * kNP1) return;
  const int b = (int)(row / kNP1);
  const int n = (int)(row % kNP1);
  const float* vrow = (n < kN) ? (vis + ((size_t)b * kN + n) * kC) : dustbin;
  const float* prow = prompt + (size_t)b * kC;
  float dot = 0.f, vsq = 0.f, psq = 0.f;
#pragma unroll
  for (int h = 0; h < 2; ++h) {
    const int off = h * 256 + lane * 4;
    const float4 v4 = *reinterpret_cast<const float4*>(vrow + off);
    const float4 p4 = *reinterpret_cast<const float4*>(prow + off);
    dot += v4.x * p4.x + v4.y * p4.y + v4.z * p4.z + v4.w * p4.w;
    vsq += v4.x * v4.x + v4.y * v4.y + v4.z * v4.z + v4.w * v4.w;
    psq += p4.x * p4.x + p4.y * p4.y + p4.z * p4.z + p4.w * p4.w;
  }
#pragma unroll
  for (int s = 1; s < 64; s <<= 1) {
    dot += __shfl_xor(dot, s);
    vsq += __shfl_xor(vsq, s);
    psq += __shfl_xor(psq, s);
  }
  if (lane == 0) {
    const float pn = fmaxf(sqrtf(psq), 1e-12f);
    const float vn = fmaxf(sqrtf(vsq), 1e-12f);
    sim[row] = dot / (pn * vn);
  }
}

__global__ __launch_bounds__(1024) void sinkhorn_kernel(
    const float* __restrict__ sim, float* __restrict__ gamma,
    float* __restrict__ mass_out) {
  const int b = blockIdx.x;
  const int t = threadIdx.x;
  __shared__ float red[16];
  const float* simb = sim + (size_t)b * kNP1;
  const float K0 = exp2f((simb[t] - 1.0f) * kSCALE);
  const float K1 = (t == 0) ? exp2f((simb[kN] - 1.0f) * kSCALE) : 0.0f;
  float v0 = 1.0f, v1 = 1.0f, u = 1.0f;
  for (int it = 0; it < 3; ++it) {
    float partial = K0 * v0 + K1 * v1;
#pragma unroll
    for (int s = 1; s < 64; s <<= 1) partial += __shfl_xor(partial, s);
    if ((t & 63) == 0) red[t >> 6] = partial;
    __syncthreads();
    float Kv = 0.f;
#pragma unroll
    for (int w = 0; w < 16; ++w) Kv += red[w];
    __syncthreads();
    u = exp2f(-kPOW * log2f(Kv + kEPS));
    v0 = exp2f(-kPOW * log2f(u * K0 + kEPS));
    v1 = exp2f(-kPOW * log2f(u * K1 + kEPS));
  }
  const float g0 = u * K0 * v0;
  gamma[(size_t)b * kN + t] = g0;
  float partial = g0;
#pragma unroll
  for (int s = 1; s < 64; s <<= 1) partial += __shfl_xor(partial, s);
  if ((t & 63) == 0) red[t >> 6] = partial;
  __syncthreads();
  if (t == 0) {
    float m = 0.f;
#pragma unroll
    for (int w = 0; w < 16; ++w) m += red[w];
    mass_out[b] = m;
  }
}

__global__ __launch_bounds__(512) void pobs_kernel(
    const float* __restrict__ vis, const float* __restrict__ gamma,
    float* __restrict__ partial) {
  const int b = blockIdx.x / kNSplit;
  const int s = blockIdx.x % kNSplit;
  const int c = threadIdx.x;
  __shared__ float gsm[kRowsPerSplit];
  const float* g = gamma + (size_t)b * kN + (size_t)s * kRowsPerSplit;
  for (int i = threadIdx.x; i < kRowsPerSplit; i += 512) gsm[i] = g[i];
  __syncthreads();
  const float* vbase = vis + ((size_t)b * kN + (size_t)s * kRowsPerSplit) * kC;
  float acc = 0.f;
#pragma unroll 8
  for (int n = 0; n < kRowsPerSplit; ++n)
    acc += gsm[n] * vbase[(size_t)n * kC + c];
  partial[(size_t)blockIdx.x * kC + c] = acc;
}

__global__ __launch_bounds__(256) void reduce_kernel(
    const float* __restrict__ partial, float* __restrict__ p_obs) {
  const int i = blockIdx.x * 256 + threadIdx.x;
  if (i >= kB * kC) return;
  const int b = i / kC;
  const int c = i % kC;
  float s = 0.f;
#pragma unroll
  for (int k = 0; k < kNSplit; ++k)
    s += partial[((size_t)(b * kNSplit + k)) * kC + c];
  p_obs[i] = s;
}

// ===========================================================================

extern "C" void kernel_launch(void* const* d_in, const int* in_sizes, int n_in,
                              void* d_out, int out_size, void* d_ws,
                              size_t ws_size, hipStream_t stream) {
  const float* prompt = (const float*)d_in[0];
  const float* vis = (const float*)d_in[1];
  const float* dustbin = (const float*)d_in[2];
  float* out = (float*)d_out;  // p_obs [B*C] then total_mass [B]

  if (ws_size >= kWsNeeded) {
    float* sim = (float*)d_ws;
    float* partials = (float*)((unsigned char*)d_ws + kPartOffB);
    sim_moment_kernel<<<kB * 4, 256, 0, stream>>>(prompt, vis, dustbin, sim,
                                                  partials);
    sinkhorn_combine_kernel<<<kB, 1024, 0, stream>>>(
        sim, partials, out, out + (size_t)kB * kC);
  } else {
    float* ws = (float*)d_ws;
    float* sim = ws + kFbSimOff;
    float* gamma = ws + kFbGammaOff;
    float* partial = ws + kFbPartialOff;
    const long long rows = (long long)kB * kNP1;
    sim_kernel<<<(int)((rows + 3) / 4), 256, 0, stream>>>(prompt, vis,
                                                          dustbin, sim);
    sinkhorn_kernel<<<kB, 1024, 0, stream>>>(sim, gamma, out + (size_t)kB * kC);
    pobs_kernel<<<kB * kNSplit, 512, 0, stream>>>(vis, gamma, partial);
    reduce_kernel<<<(kB * kC + 255) / 256, 256, 0, stream>>>(partial, out);
  }
}